// Round 6
// baseline (258.707 us; speedup 1.0000x reference)
//
#include <hip/hip_runtime.h>
#include <hip/hip_bf16.h>

#define NN 4096
#define FF 512
#define NH 8
#define DH 64

typedef __attribute__((ext_vector_type(8))) short bf16x8;
typedef __attribute__((ext_vector_type(4))) float f32x4;

// ws layout in ushort elements:
//  X_BF  [4096][512]                    @ 0
//  W_BF  [3][512][512]                  @ 2097152   (Wq pre-scaled by 1/sqrt(512))
//  QF    [8][256 blk][2 half][64 ln][8] @ 2883584   (MFMA A-fragment order)
//  KF    [8][256 blk][2 half][64 ln][8] @ 4980736   (MFMA B-fragment order)
//  VF    [8][64 kb][4 dt][2 hf][64][8]  @ 7077888   (MFMA B-fragment order, d-major)
//  PACC  bf16 [2 ks][8 h][4096][64]     @ 9175040   (4194304 ushorts)
//  PDEN  f32  [2 ks][8 h][4096]         @ 13369344  (131072 ushorts)
//  PK    u32  [8*4096 rows][128]        @ 16777216  (bit c of dword j = adj!=0 at col 32j+c)
#define X_OFF  0
#define W_OFF  2097152
#define QF_OFF 2883584
#define KF_OFF 4980736
#define VF_OFF 7077888
#define PACC_OFF 9175040
#define PDEN_USHORT_OFF 13369344
#define PK_USHORT_OFF 16777216

__device__ __forceinline__ ushort f2bf(float f) {
    __hip_bfloat16 h = __float2bfloat16(f);
    return __builtin_bit_cast(ushort, h);
}
__device__ __forceinline__ float bf2f(ushort u) {
    unsigned int v = ((unsigned int)u) << 16;
    return __builtin_bit_cast(float, v);
}

// ---------------- kernel P: pack adj (int32) -> bitmasks, 64:1 ----------------
// One wave per row (32768 rows of 4096 cols). Lane l reads col base+l (256B/instr,
// fully coalesced), __ballot gives 64 mask bits in lane order == column order.
__global__ __launch_bounds__(256) void pack_kernel(const int* __restrict__ adj,
                                                   unsigned int* __restrict__ pk) {
    int wave = threadIdx.x >> 6, lane = threadIdx.x & 63;
    int row = blockIdx.x * 4 + wave;          // 0..32767  (= h*4096 + n)
    const int* ar = adj + (size_t)row * 4096;
    unsigned long long* outp = reinterpret_cast<unsigned long long*>(pk + (size_t)row * 128);
    for (int it = 0; it < 64; it += 4) {
        int v0 = __builtin_nontemporal_load(ar + (it + 0) * 64 + lane);
        int v1 = __builtin_nontemporal_load(ar + (it + 1) * 64 + lane);
        int v2 = __builtin_nontemporal_load(ar + (it + 2) * 64 + lane);
        int v3 = __builtin_nontemporal_load(ar + (it + 3) * 64 + lane);
        unsigned long long b0 = __ballot(v0 != 0);
        unsigned long long b1 = __ballot(v1 != 0);
        unsigned long long b2 = __ballot(v2 != 0);
        unsigned long long b3 = __ballot(v3 != 0);
        if (lane == 0) {
            outp[it + 0] = b0;
            outp[it + 1] = b1;
            outp[it + 2] = b2;
            outp[it + 3] = b3;
        }
    }
}

// ---------------- kernel 0: f32 -> bf16 convert (x, Wq*scale, Wk, Wv) ----------------
__global__ __launch_bounds__(256) void cvt_kernel(const float* __restrict__ x,
                                                  const float* __restrict__ wq,
                                                  const float* __restrict__ wk,
                                                  const float* __restrict__ wv,
                                                  ushort* __restrict__ ws) {
    int i = blockIdx.x * 256 + threadIdx.x;
    int base = i * 4;
    const float* src;
    int off;
    float sc = 1.f;
    if (base < 2097152) { src = x; off = base; }
    else {
        int t = base - 2097152;
        int m = t >> 18;
        src = (m == 0) ? wq : ((m == 1) ? wk : wv);
        if (m == 0) sc = 0.044194173824159216f;   // 1/sqrt(512) folded into Wq
        off = t & 262143;
    }
    float4 v = *reinterpret_cast<const float4*>(src + off);
    ushort4 o;
    o.x = f2bf(v.x * sc); o.y = f2bf(v.y * sc); o.z = f2bf(v.z * sc); o.w = f2bf(v.w * sc);
    *reinterpret_cast<ushort4*>(ws + base) = o;
}

// ---------------- kernel 1: QKV projection, outputs in MFMA-fragment order ----------------
__global__ __launch_bounds__(256) void qkv_kernel(ushort* __restrict__ ws) {
    int bx = blockIdx.x;
    int mat = bx >> 3;          // 0=Q,1=K,2=V
    int fb  = bx & 7;           // head
    int mb  = blockIdx.y;
    int wave = threadIdx.x >> 6, lane = threadIdx.x & 63;
    int la = lane & 15, lk = lane >> 4;

    int m_base = mb * 64 + wave * 16;
    int f_base = fb * 64;

    const ushort* xb = ws + X_OFF;
    const ushort* wb = ws + W_OFF + mat * 262144;

    f32x4 acc[4];
#pragma unroll
    for (int t = 0; t < 4; ++t) acc[t] = (f32x4){0.f, 0.f, 0.f, 0.f};

#pragma unroll 4
    for (int k0 = 0; k0 < 512; k0 += 32) {
        bf16x8 a = *reinterpret_cast<const bf16x8*>(xb + (size_t)(m_base + la) * 512 + k0 + lk * 8);
#pragma unroll
        for (int ft = 0; ft < 4; ++ft) {
            bf16x8 b = *reinterpret_cast<const bf16x8*>(wb + (size_t)(f_base + ft * 16 + la) * 512 + k0 + lk * 8);
            acc[ft] = __builtin_amdgcn_mfma_f32_16x16x32_bf16(a, b, acc[ft], 0, 0, 0);
        }
    }

#pragma unroll
    for (int ft = 0; ft < 4; ++ft) {
#pragma unroll
        for (int r = 0; r < 4; ++r) {
            int n = m_base + lk * 4 + r;
            int d = ft * 16 + la;          // head-local feature
            ushort v = f2bf(acc[ft][r]);
            if (mat < 2) {
                ushort* base = ws + (mat == 0 ? QF_OFF : KF_OFF) + (size_t)fb * 262144;
                int blk = n >> 4, rr = n & 15;
                int half = d >> 5, lkk = (d >> 3) & 3, e = d & 7;
                base[(((size_t)blk * 2 + half) * 64 + lkk * 16 + rr) * 8 + e] = v;
            } else {
                ushort* base = ws + VF_OFF + (size_t)fb * 262144;
                int kb64 = n >> 6, kc = n & 63;
                int hf = kc >> 5, lkv = (kc >> 3) & 3, ev = kc & 7;
                int dt = d >> 4, lav = d & 15;
                base[((((size_t)kb64 * 4 + dt) * 2 + hf) * 64 + lkv * 16 + lav) * 8 + ev] = v;
            }
        }
    }
}

// ---------------- kernel 2: masked attention from packed bitmasks ----------------
// grid 512: h = bid&7 (XCD-pinned: K/V 1MB + masks 2MB live in that XCD's L2),
// qb = (bid>>3)&31, ks = bid>>8 (0..1). 4 waves x 32 q-rows, 2048 keys each.
// Main loop touches HBM zero times: K/V/mask all L2-resident.

#define ATTN_BODY(M_CUR, M_NXT, KB, KBN)                                                  \
    {                                                                                     \
        const int kb64_ = (KB);                                                           \
        bf16x8 kf[4][2], vb[4][2];                                                        \
        _Pragma("unroll")                                                                 \
        for (int kt = 0; kt < 4; ++kt) {                                                  \
            const ushort* kp = Kh + (((size_t)(kb64_ * 4 + kt) * 2) * 64 + lane) * 8;     \
            kf[kt][0] = *reinterpret_cast<const bf16x8*>(kp);                             \
            kf[kt][1] = *reinterpret_cast<const bf16x8*>(kp + 512);                       \
        }                                                                                 \
        _Pragma("unroll")                                                                 \
        for (int dt = 0; dt < 4; ++dt) {                                                  \
            const ushort* vp = Vh + ((((size_t)kb64_ * 4 + dt) * 2) * 64 + lane) * 8;     \
            vb[dt][0] = *reinterpret_cast<const bf16x8*>(vp);                             \
            vb[dt][1] = *reinterpret_cast<const bf16x8*>(vp + 512);                       \
        }                                                                                 \
        _Pragma("unroll")                                                                 \
        for (int qs = 0; qs < 2; ++qs)                                                    \
            _Pragma("unroll")                                                             \
            for (int r = 0; r < 4; ++r)                                                   \
                M_NXT[qs][r] = *reinterpret_cast<const uint2*>(pkh + rowpk[qs][r] + (KBN) * 2); \
        f32x4 s[2][4];                                                                    \
        _Pragma("unroll")                                                                 \
        for (int kt = 0; kt < 4; ++kt)                                                    \
            _Pragma("unroll")                                                             \
            for (int qs = 0; qs < 2; ++qs) {                                              \
                s[qs][kt] = __builtin_amdgcn_mfma_f32_16x16x32_bf16(qa[qs][0], kf[kt][0], zero, 0, 0, 0); \
                s[qs][kt] = __builtin_amdgcn_mfma_f32_16x16x32_bf16(qa[qs][1], kf[kt][1], s[qs][kt], 0, 0, 0); \
            }                                                                             \
        _Pragma("unroll")                                                                 \
        for (int qs = 0; qs < 2; ++qs)                                                    \
            _Pragma("unroll")                                                             \
            for (int kt = 0; kt < 4; ++kt) {                                              \
                _Pragma("unroll")                                                         \
                for (int r = 0; r < 4; ++r) {                                             \
                    unsigned int dw = (kt < 2) ? M_CUR[qs][r].x : M_CUR[qs][r].y;         \
                    float sv = ((dw >> (la + ((kt & 1) << 4))) & 1u) ? s[qs][kt][r] : -1e30f; \
                    float e = __expf(sv);                                                 \
                    den[qs][r] += e;                                                      \
                    P[wave][qs * 16 + lk * 4 + r][kt * 16 + la] = f2bf(e);                \
                }                                                                         \
            }                                                                             \
        _Pragma("unroll")                                                                 \
        for (int qs = 0; qs < 2; ++qs) {                                                  \
            bf16x8 pa0 = *reinterpret_cast<const bf16x8*>(&P[wave][qs * 16 + la][lk * 8]);      \
            bf16x8 pa1 = *reinterpret_cast<const bf16x8*>(&P[wave][qs * 16 + la][32 + lk * 8]); \
            _Pragma("unroll")                                                             \
            for (int dt = 0; dt < 4; ++dt) {                                              \
                acc[qs][dt] = __builtin_amdgcn_mfma_f32_16x16x32_bf16(pa0, vb[dt][0], acc[qs][dt], 0, 0, 0); \
                acc[qs][dt] = __builtin_amdgcn_mfma_f32_16x16x32_bf16(pa1, vb[dt][1], acc[qs][dt], 0, 0, 0); \
            }                                                                             \
        }                                                                                 \
    }

__global__ __launch_bounds__(256, 2) void attn_kernel(const unsigned int* __restrict__ pk,
                                                      const ushort* __restrict__ ws,
                                                      ushort* __restrict__ pacc,
                                                      float* __restrict__ pden) {
    __shared__ ushort P[4][32][72];

    int bid = blockIdx.x;
    int h = bid & 7, qb = (bid >> 3) & 31, ks = bid >> 8;
    int wave = threadIdx.x >> 6, lane = threadIdx.x & 63;
    int la = lane & 15, lk = lane >> 4;
    int q0 = qb * 128 + wave * 32;

    const ushort* Qh = ws + QF_OFF + (size_t)h * 262144;
    const ushort* Kh = ws + KF_OFF + (size_t)h * 262144;
    const ushort* Vh = ws + VF_OFF + (size_t)h * 262144;
    const unsigned int* pkh = pk + (size_t)h * 4096 * 128;

    bf16x8 qa[2][2];
#pragma unroll
    for (int qs = 0; qs < 2; ++qs)
#pragma unroll
        for (int hf = 0; hf < 2; ++hf)
            qa[qs][hf] = *reinterpret_cast<const bf16x8*>(
                Qh + ((((size_t)((q0 >> 4) + qs)) * 2 + hf) * 64 + lane) * 8);

    f32x4 acc[2][4];
    float den[2][4];
    int rowpk[2][4];
#pragma unroll
    for (int qs = 0; qs < 2; ++qs)
#pragma unroll
        for (int r = 0; r < 4; ++r) {
            acc[qs][r] = (f32x4){0.f, 0.f, 0.f, 0.f};
            den[qs][r] = 0.f;
            rowpk[qs][r] = (q0 + qs * 16 + lk * 4 + r) * 128;
        }

    const f32x4 zero = {0.f, 0.f, 0.f, 0.f};
    int kbase = ks * 32;

    uint2 mA[2][4], mB[2][4];
    {   // prologue: masks for first body
#pragma unroll
        for (int qs = 0; qs < 2; ++qs)
#pragma unroll
            for (int r = 0; r < 4; ++r)
                mA[qs][r] = *reinterpret_cast<const uint2*>(pkh + rowpk[qs][r] + kbase * 2);
    }

    for (int it = 0; it < 32; it += 2) {
        int k0 = kbase + it;
        int k2n = (it + 2 < 32) ? (k0 + 2) : kbase;   // clamp last prefetch (unused, valid addr)
        ATTN_BODY(mA, mB, k0, k0 + 1)
        ATTN_BODY(mB, mA, k0 + 1, k2n)
    }

    // reduce den over the 16-lane key dimension
#pragma unroll
    for (int qs = 0; qs < 2; ++qs)
#pragma unroll
        for (int r = 0; r < 4; ++r)
#pragma unroll
            for (int m = 1; m < 16; m <<= 1)
                den[qs][r] += __shfl_xor(den[qs][r], m, 64);

    // store bf16 partial acc + f32 partial den
    ushort* pa_out = pacc + ((size_t)ks * 8 + h) * 4096 * 64;
#pragma unroll
    for (int qs = 0; qs < 2; ++qs)
#pragma unroll
        for (int dt = 0; dt < 4; ++dt)
#pragma unroll
            for (int r = 0; r < 4; ++r) {
                int q = q0 + qs * 16 + lk * 4 + r;
                __builtin_nontemporal_store(f2bf(acc[qs][dt][r]), pa_out + (size_t)q * 64 + dt * 16 + la);
            }
    if (la == 0) {
        float* pd = pden + ((size_t)ks * 8 + h) * 4096;
#pragma unroll
        for (int qs = 0; qs < 2; ++qs)
#pragma unroll
            for (int r = 0; r < 4; ++r)
                pd[q0 + qs * 16 + lk * 4 + r] = den[qs][r];
    }
}

// ---------------- kernel 3: combine bf16 partials + epilogue ----------------
__global__ __launch_bounds__(256) void combine_kernel(const float* __restrict__ x,
                                                      const ushort* __restrict__ pacc,
                                                      const float* __restrict__ pden,
                                                      float* __restrict__ out) {
    int idx = blockIdx.x * 256 + threadIdx.x;   // 524288 total
    int n = idx >> 7, fq = idx & 127;
    int h = fq >> 4;
    int d4 = (fq & 15) * 4;

    float4 o = make_float4(0.f, 0.f, 0.f, 0.f);
    float den = 0.f;
#pragma unroll
    for (int ksp = 0; ksp < 2; ++ksp) {
        const ushort* pa = pacc + (((size_t)ksp * 8 + h) * 4096 + n) * 64 + d4;
        ushort4 p = *reinterpret_cast<const ushort4*>(pa);
        o.x += bf2f(p.x); o.y += bf2f(p.y); o.z += bf2f(p.z); o.w += bf2f(p.w);
        den += pden[((size_t)ksp * 8 + h) * 4096 + n];
    }
    float4 xv = *reinterpret_cast<const float4*>(x + (size_t)n * 512 + fq * 4);
    float inv = 1.f / den;
    float4 r;
    r.x = o.x * inv + xv.x;
    r.y = o.y * inv + xv.y;
    r.z = o.z * inv + xv.z;
    r.w = o.w * inv + xv.w;
    r.x = (r.x > 0.f) ? r.x : (__expf(r.x) - 1.f);
    r.y = (r.y > 0.f) ? r.y : (__expf(r.y) - 1.f);
    r.z = (r.z > 0.f) ? r.z : (__expf(r.z) - 1.f);
    r.w = (r.w > 0.f) ? r.w : (__expf(r.w) - 1.f);
    *reinterpret_cast<float4*>(out + (size_t)n * 512 + fq * 4) = r;
}

extern "C" void kernel_launch(void* const* d_in, const int* in_sizes, int n_in,
                              void* d_out, int out_size, void* d_ws, size_t ws_size,
                              hipStream_t stream) {
    const float* x  = (const float*)d_in[0];
    const float* wq = (const float*)d_in[1];
    const float* wk = (const float*)d_in[2];
    const float* wv = (const float*)d_in[3];
    const int*   adj = (const int*)d_in[4];
    float* out = (float*)d_out;
    ushort* ws = (ushort*)d_ws;
    ushort* pacc = ws + PACC_OFF;
    float* pden = (float*)(ws + PDEN_USHORT_OFF);
    unsigned int* pk = (unsigned int*)(ws + PK_USHORT_OFF);

    pack_kernel<<<8192, 256, 0, stream>>>(adj, pk);
    cvt_kernel<<<2816, 256, 0, stream>>>(x, wq, wk, wv, ws);
    qkv_kernel<<<dim3(24, 64), 256, 0, stream>>>(ws);
    attn_kernel<<<512, 256, 0, stream>>>(pk, ws, pacc, pden);
    combine_kernel<<<2048, 256, 0, stream>>>(x, pacc, pden, out);
}

// Round 7
// 243.860 us; speedup vs baseline: 1.0609x; 1.0609x over previous
//
#include <hip/hip_runtime.h>
#include <hip/hip_bf16.h>

#define NN 4096
#define FF 512
#define NH 8
#define DH 64

typedef __attribute__((ext_vector_type(8))) short bf16x8;
typedef __attribute__((ext_vector_type(4))) float f32x4;

// ws layout in ushort elements:
//  X_BF  [4096][512]                    @ 0
//  W_BF  [3][512][512]                  @ 2097152   (Wq pre-scaled by 1/sqrt(512))
//  QF    [8][256 blk][2 half][64 ln][8] @ 2883584   (MFMA A-fragment order)
//  KF    [8][256 blk][2 half][64 ln][8] @ 4980736   (MFMA B-fragment order)
//  VF    [8][64 kb][4 dt][2 hf][64][8]  @ 7077888   (MFMA B-fragment order, d-major)
//  PACC  bf16 [4 ks][8 h][4096][64]     @ 9175040   (8388608 ushorts)
//  PDEN  f32  [4 ks][8 h][4096]         @ 17563648  (262144 ushorts)
#define X_OFF  0
#define W_OFF  2097152
#define QF_OFF 2883584
#define KF_OFF 4980736
#define VF_OFF 7077888
#define PACC_OFF 9175040
#define PDEN_USHORT_OFF 17563648

__device__ __forceinline__ ushort f2bf(float f) {
    __hip_bfloat16 h = __float2bfloat16(f);
    return __builtin_bit_cast(ushort, h);
}
__device__ __forceinline__ float bf2f(ushort u) {
    unsigned int v = ((unsigned int)u) << 16;
    return __builtin_bit_cast(float, v);
}

// ---------------- kernel 0: f32 -> bf16 convert (x, Wq*scale, Wk, Wv) ----------------
__global__ __launch_bounds__(256) void cvt_kernel(const float* __restrict__ x,
                                                  const float* __restrict__ wq,
                                                  const float* __restrict__ wk,
                                                  const float* __restrict__ wv,
                                                  ushort* __restrict__ ws) {
    int i = blockIdx.x * 256 + threadIdx.x;
    int base = i * 4;
    const float* src;
    int off;
    float sc = 1.f;
    if (base < 2097152) { src = x; off = base; }
    else {
        int t = base - 2097152;
        int m = t >> 18;
        src = (m == 0) ? wq : ((m == 1) ? wk : wv);
        if (m == 0) sc = 0.044194173824159216f;   // 1/sqrt(512) folded into Wq
        off = t & 262143;
    }
    float4 v = *reinterpret_cast<const float4*>(src + off);
    ushort4 o;
    o.x = f2bf(v.x * sc); o.y = f2bf(v.y * sc); o.z = f2bf(v.z * sc); o.w = f2bf(v.w * sc);
    *reinterpret_cast<ushort4*>(ws + base) = o;
}

// ---------------- kernel 1: QKV projection, outputs in MFMA-fragment order ----------------
__global__ __launch_bounds__(256) void qkv_kernel(ushort* __restrict__ ws) {
    int bx = blockIdx.x;
    int mat = bx >> 3;          // 0=Q,1=K,2=V
    int fb  = bx & 7;           // head
    int mb  = blockIdx.y;
    int wave = threadIdx.x >> 6, lane = threadIdx.x & 63;
    int la = lane & 15, lk = lane >> 4;

    int m_base = mb * 64 + wave * 16;
    int f_base = fb * 64;

    const ushort* xb = ws + X_OFF;
    const ushort* wb = ws + W_OFF + mat * 262144;

    f32x4 acc[4];
#pragma unroll
    for (int t = 0; t < 4; ++t) acc[t] = (f32x4){0.f, 0.f, 0.f, 0.f};

#pragma unroll 4
    for (int k0 = 0; k0 < 512; k0 += 32) {
        bf16x8 a = *reinterpret_cast<const bf16x8*>(xb + (size_t)(m_base + la) * 512 + k0 + lk * 8);
#pragma unroll
        for (int ft = 0; ft < 4; ++ft) {
            bf16x8 b = *reinterpret_cast<const bf16x8*>(wb + (size_t)(f_base + ft * 16 + la) * 512 + k0 + lk * 8);
            acc[ft] = __builtin_amdgcn_mfma_f32_16x16x32_bf16(a, b, acc[ft], 0, 0, 0);
        }
    }

#pragma unroll
    for (int ft = 0; ft < 4; ++ft) {
#pragma unroll
        for (int r = 0; r < 4; ++r) {
            int n = m_base + lk * 4 + r;
            int d = ft * 16 + la;          // head-local feature
            ushort v = f2bf(acc[ft][r]);
            if (mat < 2) {
                ushort* base = ws + (mat == 0 ? QF_OFF : KF_OFF) + (size_t)fb * 262144;
                int blk = n >> 4, rr = n & 15;
                int half = d >> 5, lkk = (d >> 3) & 3, e = d & 7;
                base[(((size_t)blk * 2 + half) * 64 + lkk * 16 + rr) * 8 + e] = v;
            } else {
                ushort* base = ws + VF_OFF + (size_t)fb * 262144;
                int kb64 = n >> 6, kc = n & 63;
                int hf = kc >> 5, lkv = (kc >> 3) & 3, ev = kc & 7;
                int dt = d >> 4, lav = d & 15;
                base[((((size_t)kb64 * 4 + dt) * 2 + hf) * 64 + lkv * 16 + lav) * 8 + ev] = v;
            }
        }
    }
}

// ---------------- kernel 2: masked attention, ballot-fused adj, k-split ----------------
// grid 2048: h = bid&7 (XCD-pinned K/V/Q), qb = (bid>>3)&63, ks = bid>>9 (0..3).
// 4 waves x 16 q-rows; 1024 keys per block (16 bodies of 64).
// Per body: ballot(adj prefetched last body) -> SGPR masks; kf loads -> QK MFMA;
// vb loads; adj prefetch (next body); mask+exp (no memory deps); P->LDS; PV MFMA.
__global__ __launch_bounds__(256, 4) void attn_kernel(const int* __restrict__ adj,
                                                      const ushort* __restrict__ ws,
                                                      ushort* __restrict__ pacc,
                                                      float* __restrict__ pden) {
    __shared__ ushort P[4][16][72];

    int bid = blockIdx.x;
    int h = bid & 7, qb = (bid >> 3) & 63, ks = bid >> 9;
    int wave = threadIdx.x >> 6, lane = threadIdx.x & 63;
    int la = lane & 15, lk = lane >> 4;
    int q0w = qb * 64 + wave * 16;

    const ushort* Qh = ws + QF_OFF + (size_t)h * 262144;
    const ushort* Kh = ws + KF_OFF + (size_t)h * 262144;
    const ushort* Vh = ws + VF_OFF + (size_t)h * 262144;
    const int* adjw = adj + (size_t)h * 16777216 + (size_t)q0w * 4096;

    bf16x8 qa0 = *reinterpret_cast<const bf16x8*>(Qh + ((((size_t)(q0w >> 4)) * 2 + 0) * 64 + lane) * 8);
    bf16x8 qa1 = *reinterpret_cast<const bf16x8*>(Qh + ((((size_t)(q0w >> 4)) * 2 + 1) * 64 + lane) * 8);

    f32x4 acc[4];
    float den[4];
#pragma unroll
    for (int r = 0; r < 4; ++r) {
        acc[r] = (f32x4){0.f, 0.f, 0.f, 0.f};
        den[r] = 0.f;
    }

    const f32x4 zero = {0.f, 0.f, 0.f, 0.f};
    int kbase = ks * 16;          // body index base; body kb covers keys kb*64..+63

    // prologue: adj for first body (rows = this wave's 16 q-rows, cols = body keys + lane)
    int adjv[16];
#pragma unroll
    for (int j = 0; j < 16; ++j)
        adjv[j] = __builtin_nontemporal_load(adjw + (size_t)j * 4096 + kbase * 64 + lane);

    for (int it = 0; it < 16; ++it) {
        int kb = kbase + it;

        // ballots -> wave-uniform masks (SGPR); bit l of m[j] = adj[row j][kb*64+l]
        unsigned long long m[16];
#pragma unroll
        for (int j = 0; j < 16; ++j)
            m[j] = __ballot(adjv[j] != 0);

        // per-lane 4-way row select (row = lk*4+r), split into lo/hi key dwords
        unsigned int sel_lo[4], sel_hi[4];
#pragma unroll
        for (int r = 0; r < 4; ++r) {
            unsigned int l0 = (unsigned int)m[r],       h0 = (unsigned int)(m[r] >> 32);
            unsigned int l1 = (unsigned int)m[4 + r],   h1 = (unsigned int)(m[4 + r] >> 32);
            unsigned int l2 = (unsigned int)m[8 + r],   h2 = (unsigned int)(m[8 + r] >> 32);
            unsigned int l3 = (unsigned int)m[12 + r],  h3 = (unsigned int)(m[12 + r] >> 32);
            unsigned int a = (lk & 1) ? l1 : l0, b = (lk & 1) ? l3 : l2;
            sel_lo[r] = (lk & 2) ? b : a;
            unsigned int c = (lk & 1) ? h1 : h0, d = (lk & 1) ? h3 : h2;
            sel_hi[r] = (lk & 2) ? d : c;
        }

        // K fragment loads + QK^T
        bf16x8 kf[4][2];
#pragma unroll
        for (int kt = 0; kt < 4; ++kt) {
            const ushort* kp = Kh + (((size_t)(kb * 4 + kt) * 2) * 64 + lane) * 8;
            kf[kt][0] = *reinterpret_cast<const bf16x8*>(kp);
            kf[kt][1] = *reinterpret_cast<const bf16x8*>(kp + 512);
        }
        f32x4 s[4];
#pragma unroll
        for (int kt = 0; kt < 4; ++kt) {
            s[kt] = __builtin_amdgcn_mfma_f32_16x16x32_bf16(qa0, kf[kt][0], zero, 0, 0, 0);
            s[kt] = __builtin_amdgcn_mfma_f32_16x16x32_bf16(qa1, kf[kt][1], s[kt], 0, 0, 0);
        }

        // V fragment loads (consumed in PV below)
        bf16x8 vb[4][2];
#pragma unroll
        for (int dt = 0; dt < 4; ++dt) {
            const ushort* vp = Vh + ((((size_t)kb * 4 + dt) * 2) * 64 + lane) * 8;
            vb[dt][0] = *reinterpret_cast<const bf16x8*>(vp);
            vb[dt][1] = *reinterpret_cast<const bf16x8*>(vp + 512);
        }

        // adj prefetch for next body (newest loads; PV's vb wait leaves these in flight)
        int kbn = (it + 1 < 16) ? kb + 1 : kbase;
#pragma unroll
        for (int j = 0; j < 16; ++j)
            adjv[j] = __builtin_nontemporal_load(adjw + (size_t)j * 4096 + kbn * 64 + lane);

        // mask + exp + P->LDS (no memory dependencies: masks in regs, s from MFMA)
#pragma unroll
        for (int r = 0; r < 4; ++r) {
#pragma unroll
            for (int kt = 0; kt < 4; ++kt) {
                unsigned int dw = (kt < 2) ? sel_lo[r] : sel_hi[r];
                unsigned int bit = (dw >> (la + ((kt & 1) << 4))) & 1u;
                float sv = bit ? s[kt][r] : -1e30f;
                float e = __expf(sv);
                den[r] += e;
                P[wave][lk * 4 + r][kt * 16 + la] = f2bf(e);
            }
        }

        // PV: same-wave LDS write->read (lgkmcnt ordered, no barrier)
        bf16x8 pa0 = *reinterpret_cast<const bf16x8*>(&P[wave][la][lk * 8]);
        bf16x8 pa1 = *reinterpret_cast<const bf16x8*>(&P[wave][la][32 + lk * 8]);
#pragma unroll
        for (int dt = 0; dt < 4; ++dt) {
            acc[dt] = __builtin_amdgcn_mfma_f32_16x16x32_bf16(pa0, vb[dt][0], acc[dt], 0, 0, 0);
            acc[dt] = __builtin_amdgcn_mfma_f32_16x16x32_bf16(pa1, vb[dt][1], acc[dt], 0, 0, 0);
        }
    }

    // reduce den over the 16-lane key dimension
#pragma unroll
    for (int r = 0; r < 4; ++r)
#pragma unroll
        for (int mm = 1; mm < 16; mm <<= 1)
            den[r] += __shfl_xor(den[r], mm, 64);

    // store bf16 partial acc + f32 partial den
    ushort* pa_out = pacc + ((size_t)ks * 8 + h) * 4096 * 64;
#pragma unroll
    for (int dt = 0; dt < 4; ++dt)
#pragma unroll
        for (int r = 0; r < 4; ++r) {
            int q = q0w + lk * 4 + r;
            __builtin_nontemporal_store(f2bf(acc[dt][r]), pa_out + (size_t)q * 64 + dt * 16 + la);
        }
    if (la == 0) {
        float* pd = pden + ((size_t)ks * 8 + h) * 4096;
#pragma unroll
        for (int r = 0; r < 4; ++r)
            pd[q0w + lk * 4 + r] = den[r];
    }
}

// ---------------- kernel 3: combine bf16 partials + epilogue ----------------
__global__ __launch_bounds__(256) void combine_kernel(const float* __restrict__ x,
                                                      const ushort* __restrict__ pacc,
                                                      const float* __restrict__ pden,
                                                      float* __restrict__ out) {
    int idx = blockIdx.x * 256 + threadIdx.x;   // 524288 total
    int n = idx >> 7, fq = idx & 127;
    int h = fq >> 4;
    int d4 = (fq & 15) * 4;

    float4 o = make_float4(0.f, 0.f, 0.f, 0.f);
    float den = 0.f;
#pragma unroll
    for (int ksp = 0; ksp < 4; ++ksp) {
        const ushort* pa = pacc + (((size_t)ksp * 8 + h) * 4096 + n) * 64 + d4;
        ushort4 p = *reinterpret_cast<const ushort4*>(pa);
        o.x += bf2f(p.x); o.y += bf2f(p.y); o.z += bf2f(p.z); o.w += bf2f(p.w);
        den += pden[((size_t)ksp * 8 + h) * 4096 + n];
    }
    float4 xv = *reinterpret_cast<const float4*>(x + (size_t)n * 512 + fq * 4);
    float inv = 1.f / den;
    float4 r;
    r.x = o.x * inv + xv.x;
    r.y = o.y * inv + xv.y;
    r.z = o.z * inv + xv.z;
    r.w = o.w * inv + xv.w;
    r.x = (r.x > 0.f) ? r.x : (__expf(r.x) - 1.f);
    r.y = (r.y > 0.f) ? r.y : (__expf(r.y) - 1.f);
    r.z = (r.z > 0.f) ? r.z : (__expf(r.z) - 1.f);
    r.w = (r.w > 0.f) ? r.w : (__expf(r.w) - 1.f);
    *reinterpret_cast<float4*>(out + (size_t)n * 512 + fq * 4) = r;
}

extern "C" void kernel_launch(void* const* d_in, const int* in_sizes, int n_in,
                              void* d_out, int out_size, void* d_ws, size_t ws_size,
                              hipStream_t stream) {
    const float* x  = (const float*)d_in[0];
    const float* wq = (const float*)d_in[1];
    const float* wk = (const float*)d_in[2];
    const float* wv = (const float*)d_in[3];
    const int*   adj = (const int*)d_in[4];
    float* out = (float*)d_out;
    ushort* ws = (ushort*)d_ws;
    ushort* pacc = ws + PACC_OFF;
    float* pden = (float*)(ws + PDEN_USHORT_OFF);

    cvt_kernel<<<2816, 256, 0, stream>>>(x, wq, wk, wv, ws);
    qkv_kernel<<<dim3(24, 64), 256, 0, stream>>>(ws);
    attn_kernel<<<2048, 256, 0, stream>>>(adj, ws, pacc, pden);
    combine_kernel<<<2048, 256, 0, stream>>>(x, pacc, pden, out);
}

// Round 8
// 222.673 us; speedup vs baseline: 1.1618x; 1.0951x over previous
//
#include <hip/hip_runtime.h>
#include <hip/hip_bf16.h>

#define NN 4096
#define FF 512
#define NH 8
#define DH 64

typedef __attribute__((ext_vector_type(8))) short bf16x8;
typedef __attribute__((ext_vector_type(4))) float f32x4;

// ws layout in ushort elements:
//  X_BF  [4096][512]                    @ 0
//  W_BF  [3][512][512]                  @ 2097152   (Wq pre-scaled by 1/sqrt(512))
//  QF    [8][256 blk][2 half][64 ln][8] @ 2883584   (MFMA A-fragment order)
//  KF    [8][256 blk][2 half][64 ln][8] @ 4980736   (MFMA B-fragment order)
//  VF    [8][64 kb][4 dt][2 hf][64][8]  @ 7077888   (MFMA B-fragment order, d-major)
//  PACC  bf16 [4 ks][8 h][4096][64]     @ 9175040   (8388608 ushorts)
//  PDEN  f32  [4 ks][8 h][4096]         @ 17563648  (262144 ushorts)
#define X_OFF  0
#define W_OFF  2097152
#define QF_OFF 2883584
#define KF_OFF 4980736
#define VF_OFF 7077888
#define PACC_OFF 9175040
#define PDEN_USHORT_OFF 17563648

__device__ __forceinline__ ushort f2bf(float f) {
    __hip_bfloat16 h = __float2bfloat16(f);
    return __builtin_bit_cast(ushort, h);
}
__device__ __forceinline__ float bf2f(ushort u) {
    unsigned int v = ((unsigned int)u) << 16;
    return __builtin_bit_cast(float, v);
}

// ---------------- kernel 0: f32 -> bf16 convert (x, Wq*scale, Wk, Wv) ----------------
__global__ __launch_bounds__(256) void cvt_kernel(const float* __restrict__ x,
                                                  const float* __restrict__ wq,
                                                  const float* __restrict__ wk,
                                                  const float* __restrict__ wv,
                                                  ushort* __restrict__ ws) {
    int i = blockIdx.x * 256 + threadIdx.x;
    int base = i * 4;
    const float* src;
    int off;
    float sc = 1.f;
    if (base < 2097152) { src = x; off = base; }
    else {
        int t = base - 2097152;
        int m = t >> 18;
        src = (m == 0) ? wq : ((m == 1) ? wk : wv);
        if (m == 0) sc = 0.044194173824159216f;   // 1/sqrt(512) folded into Wq
        off = t & 262143;
    }
    float4 v = *reinterpret_cast<const float4*>(src + off);
    ushort4 o;
    o.x = f2bf(v.x * sc); o.y = f2bf(v.y * sc); o.z = f2bf(v.z * sc); o.w = f2bf(v.w * sc);
    *reinterpret_cast<ushort4*>(ws + base) = o;
}

// ---------------- kernel 1: QKV projection, outputs in MFMA-fragment order ----------------
__global__ __launch_bounds__(256) void qkv_kernel(ushort* __restrict__ ws) {
    int bx = blockIdx.x;
    int mat = bx >> 3;          // 0=Q,1=K,2=V
    int fb  = bx & 7;           // head
    int mb  = blockIdx.y;
    int wave = threadIdx.x >> 6, lane = threadIdx.x & 63;
    int la = lane & 15, lk = lane >> 4;

    int m_base = mb * 64 + wave * 16;
    int f_base = fb * 64;

    const ushort* xb = ws + X_OFF;
    const ushort* wb = ws + W_OFF + mat * 262144;

    f32x4 acc[4];
#pragma unroll
    for (int t = 0; t < 4; ++t) acc[t] = (f32x4){0.f, 0.f, 0.f, 0.f};

#pragma unroll 4
    for (int k0 = 0; k0 < 512; k0 += 32) {
        bf16x8 a = *reinterpret_cast<const bf16x8*>(xb + (size_t)(m_base + la) * 512 + k0 + lk * 8);
#pragma unroll
        for (int ft = 0; ft < 4; ++ft) {
            bf16x8 b = *reinterpret_cast<const bf16x8*>(wb + (size_t)(f_base + ft * 16 + la) * 512 + k0 + lk * 8);
            acc[ft] = __builtin_amdgcn_mfma_f32_16x16x32_bf16(a, b, acc[ft], 0, 0, 0);
        }
    }

#pragma unroll
    for (int ft = 0; ft < 4; ++ft) {
#pragma unroll
        for (int r = 0; r < 4; ++r) {
            int n = m_base + lk * 4 + r;
            int d = ft * 16 + la;          // head-local feature
            ushort v = f2bf(acc[ft][r]);
            if (mat < 2) {
                ushort* base = ws + (mat == 0 ? QF_OFF : KF_OFF) + (size_t)fb * 262144;
                int blk = n >> 4, rr = n & 15;
                int half = d >> 5, lkk = (d >> 3) & 3, e = d & 7;
                base[(((size_t)blk * 2 + half) * 64 + lkk * 16 + rr) * 8 + e] = v;
            } else {
                ushort* base = ws + VF_OFF + (size_t)fb * 262144;
                int kb64 = n >> 6, kc = n & 63;
                int hf = kc >> 5, lkv = (kc >> 3) & 3, ev = kc & 7;
                int dt = d >> 4, lav = d & 15;
                base[((((size_t)kb64 * 4 + dt) * 2 + hf) * 64 + lkv * 16 + lav) * 8 + ev] = v;
            }
        }
    }
}

// ---------------- kernel 2: masked attention, LDS-staged K/V, k-split ----------------
// grid 2048: h = bid&7 (XCD-pinned), qb = (bid>>3)&63, ks = bid>>9 (0..3).
// 4 waves x 16 q-rows; 1024 keys per block (16 bodies of 64 keys).
// Per body: the 4 waves cooperatively stage next body's K/V (16KB) straight into LDS
// via global_load_lds (4 x 16B-per-lane ops each); adj dwords per-lane, prefetched
// one body ahead; compute reads K/V fragments from LDS (ds_read_b128, full-BW).

// staging: waves 0,1 -> 8 K tiles of 1KB; waves 2,3 -> 8 V tiles. Same offset formula:
// tile t (0..7): src = base + ((KB*4 + (t>>1))*2 + (t&1)) * 512 ushorts.
#define STAGE(BUF, KB)                                                                     \
    {                                                                                      \
        const ushort* sbase_ = (wave < 2) ? Kh : Vh;                                       \
        ushort(*dbuf_)[512] = (wave < 2) ? kbuf[BUF] : vbuf[BUF];                          \
        int t0_ = (wave & 1) * 4;                                                          \
        _Pragma("unroll")                                                                  \
        for (int t_ = 0; t_ < 4; ++t_) {                                                   \
            int tile_ = t0_ + t_;                                                          \
            const ushort* src_ = sbase_ +                                                  \
                (((size_t)(KB) * 4 + (tile_ >> 1)) * 2 + (tile_ & 1)) * 512 + lane * 8;    \
            __builtin_amdgcn_global_load_lds(                                              \
                (const __attribute__((address_space(1))) unsigned int*)src_,               \
                (__attribute__((address_space(3))) unsigned int*)&dbuf_[tile_][0],         \
                16, 0, 0);                                                                 \
        }                                                                                  \
    }

__global__ __launch_bounds__(256, 3) void attn_kernel(const int* __restrict__ adj,
                                                      const ushort* __restrict__ ws,
                                                      ushort* __restrict__ pacc,
                                                      float* __restrict__ pden) {
    __shared__ ushort kbuf[2][8][512];   // [buf][tile=blkoff*2+half][lane*8+e]  16KB
    __shared__ ushort vbuf[2][8][512];   // [buf][tile=dt*2+hf][lane*8+e]        16KB
    __shared__ ushort P[4][16][72];      // per-wave P staging                   9.2KB

    int bid = blockIdx.x;
    int h = bid & 7, qb = (bid >> 3) & 63, ks = bid >> 9;
    int wave = threadIdx.x >> 6, lane = threadIdx.x & 63;
    int la = lane & 15, lk = lane >> 4;
    int q0w = qb * 64 + wave * 16;

    const ushort* Qh = ws + QF_OFF + (size_t)h * 262144;
    const ushort* Kh = ws + KF_OFF + (size_t)h * 262144;
    const ushort* Vh = ws + VF_OFF + (size_t)h * 262144;
    const int* adjw = adj + (size_t)h * 16777216 + (size_t)q0w * 4096;

    bf16x8 qa0 = *reinterpret_cast<const bf16x8*>(Qh + ((((size_t)(q0w >> 4)) * 2 + 0) * 64 + lane) * 8);
    bf16x8 qa1 = *reinterpret_cast<const bf16x8*>(Qh + ((((size_t)(q0w >> 4)) * 2 + 1) * 64 + lane) * 8);

    f32x4 acc[4];
    float den[4];
#pragma unroll
    for (int r = 0; r < 4; ++r) {
        acc[r] = (f32x4){0.f, 0.f, 0.f, 0.f};
        den[r] = 0.f;
    }

    const f32x4 zero = {0.f, 0.f, 0.f, 0.f};
    int kbase = ks * 16;   // body index base; body kb covers keys kb*64 .. kb*64+63

    // prologue: stage body kbase into buf0; prefetch its adj dwords
    STAGE(0, kbase)
    int adjv[16];
#pragma unroll
    for (int kt = 0; kt < 4; ++kt)
#pragma unroll
        for (int r = 0; r < 4; ++r)
            adjv[kt * 4 + r] = __builtin_nontemporal_load(
                adjw + (size_t)(lk * 4 + r) * 4096 + (size_t)kbase * 64 + kt * 16 + la);
    __syncthreads();

    for (int it = 0; it < 16; ++it) {
        int kb = kbase + it;
        int cur = it & 1;

        // stage next body into the other buffer (completes by this body's end barrier)
        if (it < 15) STAGE(cur ^ 1, kb + 1)

        // consume adjv -> additive masks, freeing adjv for the next prefetch
        float fmask[16];
#pragma unroll
        for (int j = 0; j < 16; ++j)
            fmask[j] = adjv[j] ? 0.f : -1e30f;

        // adj prefetch for next body (issued early; consumed after next barrier)
        if (it < 15) {
#pragma unroll
            for (int kt = 0; kt < 4; ++kt)
#pragma unroll
                for (int r = 0; r < 4; ++r)
                    adjv[kt * 4 + r] = __builtin_nontemporal_load(
                        adjw + (size_t)(lk * 4 + r) * 4096 + (size_t)(kb + 1) * 64 + kt * 16 + la);
        }

        // QK^T from LDS-staged K fragments
        f32x4 s[4];
#pragma unroll
        for (int kt = 0; kt < 4; ++kt) {
            bf16x8 kf0 = *reinterpret_cast<const bf16x8*>(&kbuf[cur][kt * 2 + 0][lane * 8]);
            bf16x8 kf1 = *reinterpret_cast<const bf16x8*>(&kbuf[cur][kt * 2 + 1][lane * 8]);
            s[kt] = __builtin_amdgcn_mfma_f32_16x16x32_bf16(qa0, kf0, zero, 0, 0, 0);
            s[kt] = __builtin_amdgcn_mfma_f32_16x16x32_bf16(qa1, kf1, s[kt], 0, 0, 0);
        }

        // mask + exp + P->LDS
#pragma unroll
        for (int kt = 0; kt < 4; ++kt)
#pragma unroll
            for (int r = 0; r < 4; ++r) {
                float e = __expf(s[kt][r] + fmask[kt * 4 + r]);
                den[r] += e;
                P[wave][lk * 4 + r][kt * 16 + la] = f2bf(e);
            }

        // PV from LDS-staged V fragments (P: same-wave write->read, lgkm ordered)
        bf16x8 pa0 = *reinterpret_cast<const bf16x8*>(&P[wave][la][lk * 8]);
        bf16x8 pa1 = *reinterpret_cast<const bf16x8*>(&P[wave][la][32 + lk * 8]);
#pragma unroll
        for (int dt = 0; dt < 4; ++dt) {
            bf16x8 vb0 = *reinterpret_cast<const bf16x8*>(&vbuf[cur][dt * 2 + 0][lane * 8]);
            bf16x8 vb1 = *reinterpret_cast<const bf16x8*>(&vbuf[cur][dt * 2 + 1][lane * 8]);
            acc[dt] = __builtin_amdgcn_mfma_f32_16x16x32_bf16(pa0, vb0, acc[dt], 0, 0, 0);
            acc[dt] = __builtin_amdgcn_mfma_f32_16x16x32_bf16(pa1, vb1, acc[dt], 0, 0, 0);
        }

        __syncthreads();   // staging + all reads of buf[cur] complete
    }

    // reduce den over the 16-lane key dimension
#pragma unroll
    for (int r = 0; r < 4; ++r)
#pragma unroll
        for (int mm = 1; mm < 16; mm <<= 1)
            den[r] += __shfl_xor(den[r], mm, 64);

    // store bf16 partial acc + f32 partial den
    ushort* pa_out = pacc + ((size_t)ks * 8 + h) * 4096 * 64;
#pragma unroll
    for (int dt = 0; dt < 4; ++dt)
#pragma unroll
        for (int r = 0; r < 4; ++r) {
            int q = q0w + lk * 4 + r;
            __builtin_nontemporal_store(f2bf(acc[dt][r]), pa_out + (size_t)q * 64 + dt * 16 + la);
        }
    if (la == 0) {
        float* pd = pden + ((size_t)ks * 8 + h) * 4096;
#pragma unroll
        for (int r = 0; r < 4; ++r)
            pd[q0w + lk * 4 + r] = den[r];
    }
}

// ---------------- kernel 3: combine bf16 partials + epilogue ----------------
__global__ __launch_bounds__(256) void combine_kernel(const float* __restrict__ x,
                                                      const ushort* __restrict__ pacc,
                                                      const float* __restrict__ pden,
                                                      float* __restrict__ out) {
    int idx = blockIdx.x * 256 + threadIdx.x;   // 524288 total
    int n = idx >> 7, fq = idx & 127;
    int h = fq >> 4;
    int d4 = (fq & 15) * 4;

    float4 o = make_float4(0.f, 0.f, 0.f, 0.f);
    float den = 0.f;
#pragma unroll
    for (int ksp = 0; ksp < 4; ++ksp) {
        const ushort* pa = pacc + (((size_t)ksp * 8 + h) * 4096 + n) * 64 + d4;
        ushort4 p = *reinterpret_cast<const ushort4*>(pa);
        o.x += bf2f(p.x); o.y += bf2f(p.y); o.z += bf2f(p.z); o.w += bf2f(p.w);
        den += pden[((size_t)ksp * 8 + h) * 4096 + n];
    }
    float4 xv = *reinterpret_cast<const float4*>(x + (size_t)n * 512 + fq * 4);
    float inv = 1.f / den;
    float4 r;
    r.x = o.x * inv + xv.x;
    r.y = o.y * inv + xv.y;
    r.z = o.z * inv + xv.z;
    r.w = o.w * inv + xv.w;
    r.x = (r.x > 0.f) ? r.x : (__expf(r.x) - 1.f);
    r.y = (r.y > 0.f) ? r.y : (__expf(r.y) - 1.f);
    r.z = (r.z > 0.f) ? r.z : (__expf(r.z) - 1.f);
    r.w = (r.w > 0.f) ? r.w : (__expf(r.w) - 1.f);
    *reinterpret_cast<float4*>(out + (size_t)n * 512 + fq * 4) = r;
}

extern "C" void kernel_launch(void* const* d_in, const int* in_sizes, int n_in,
                              void* d_out, int out_size, void* d_ws, size_t ws_size,
                              hipStream_t stream) {
    const float* x  = (const float*)d_in[0];
    const float* wq = (const float*)d_in[1];
    const float* wk = (const float*)d_in[2];
    const float* wv = (const float*)d_in[3];
    const int*   adj = (const int*)d_in[4];
    float* out = (float*)d_out;
    ushort* ws = (ushort*)d_ws;
    ushort* pacc = ws + PACC_OFF;
    float* pden = (float*)(ws + PDEN_USHORT_OFF);

    cvt_kernel<<<2816, 256, 0, stream>>>(x, wq, wk, wv, ws);
    qkv_kernel<<<dim3(24, 64), 256, 0, stream>>>(ws);
    attn_kernel<<<2048, 256, 0, stream>>>(adj, ws, pacc, pden);
    combine_kernel<<<2048, 256, 0, stream>>>(x, pacc, pden, out);
}

// Round 9
// 210.565 us; speedup vs baseline: 1.2286x; 1.0575x over previous
//
#include <hip/hip_runtime.h>
#include <hip/hip_bf16.h>

#define NN 4096
#define FF 512
#define NH 8
#define DH 64

typedef __attribute__((ext_vector_type(8))) short bf16x8;
typedef __attribute__((ext_vector_type(4))) float f32x4;

// ws layout in ushort elements:
//  X_BF  [4096][512]                    @ 0
//  W_BF  [3][512][512]                  @ 2097152   (Wq pre-scaled by 1/sqrt(512))
//  QF    [8][256 blk][2 half][64 ln][8] @ 2883584   (MFMA A-fragment order)
//  KF    [8][256 blk][2 half][64 ln][8] @ 4980736   (MFMA B-fragment order)
//  VF    [8][64 kb][4 dt][2 hf][64][8]  @ 7077888   (MFMA B-fragment order, d-major)
//  PACC  bf16 [4 ks][8 h][4096][64]     @ 9175040   (8388608 ushorts)
//  PDEN  f32  [4 ks][8 h][4096]         @ 17563648  (262144 ushorts)
#define X_OFF  0
#define W_OFF  2097152
#define QF_OFF 2883584
#define KF_OFF 4980736
#define VF_OFF 7077888
#define PACC_OFF 9175040
#define PDEN_USHORT_OFF 17563648

__device__ __forceinline__ ushort f2bf(float f) {
    __hip_bfloat16 h = __float2bfloat16(f);
    return __builtin_bit_cast(ushort, h);
}
__device__ __forceinline__ float bf2f(ushort u) {
    unsigned int v = ((unsigned int)u) << 16;
    return __builtin_bit_cast(float, v);
}

// ---------------- kernel 0: f32 -> bf16 convert (x, Wq*scale, Wk, Wv) ----------------
__global__ __launch_bounds__(256) void cvt_kernel(const float* __restrict__ x,
                                                  const float* __restrict__ wq,
                                                  const float* __restrict__ wk,
                                                  const float* __restrict__ wv,
                                                  ushort* __restrict__ ws) {
    int i = blockIdx.x * 256 + threadIdx.x;
    int base = i * 4;
    const float* src;
    int off;
    float sc = 1.f;
    if (base < 2097152) { src = x; off = base; }
    else {
        int t = base - 2097152;
        int m = t >> 18;
        src = (m == 0) ? wq : ((m == 1) ? wk : wv);
        if (m == 0) sc = 0.044194173824159216f;   // 1/sqrt(512) folded into Wq
        off = t & 262143;
    }
    float4 v = *reinterpret_cast<const float4*>(src + off);
    ushort4 o;
    o.x = f2bf(v.x * sc); o.y = f2bf(v.y * sc); o.z = f2bf(v.z * sc); o.w = f2bf(v.w * sc);
    *reinterpret_cast<ushort4*>(ws + base) = o;
}

// ---------------- kernel 1: QKV projection, outputs in MFMA-fragment order ----------------
__global__ __launch_bounds__(256) void qkv_kernel(ushort* __restrict__ ws) {
    int bx = blockIdx.x;
    int mat = bx >> 3;          // 0=Q,1=K,2=V
    int fb  = bx & 7;           // head
    int mb  = blockIdx.y;
    int wave = threadIdx.x >> 6, lane = threadIdx.x & 63;
    int la = lane & 15, lk = lane >> 4;

    int m_base = mb * 64 + wave * 16;
    int f_base = fb * 64;

    const ushort* xb = ws + X_OFF;
    const ushort* wb = ws + W_OFF + mat * 262144;

    f32x4 acc[4];
#pragma unroll
    for (int t = 0; t < 4; ++t) acc[t] = (f32x4){0.f, 0.f, 0.f, 0.f};

#pragma unroll 4
    for (int k0 = 0; k0 < 512; k0 += 32) {
        bf16x8 a = *reinterpret_cast<const bf16x8*>(xb + (size_t)(m_base + la) * 512 + k0 + lk * 8);
#pragma unroll
        for (int ft = 0; ft < 4; ++ft) {
            bf16x8 b = *reinterpret_cast<const bf16x8*>(wb + (size_t)(f_base + ft * 16 + la) * 512 + k0 + lk * 8);
            acc[ft] = __builtin_amdgcn_mfma_f32_16x16x32_bf16(a, b, acc[ft], 0, 0, 0);
        }
    }

#pragma unroll
    for (int ft = 0; ft < 4; ++ft) {
#pragma unroll
        for (int r = 0; r < 4; ++r) {
            int n = m_base + lk * 4 + r;
            int d = ft * 16 + la;          // head-local feature
            ushort v = f2bf(acc[ft][r]);
            if (mat < 2) {
                ushort* base = ws + (mat == 0 ? QF_OFF : KF_OFF) + (size_t)fb * 262144;
                int blk = n >> 4, rr = n & 15;
                int half = d >> 5, lkk = (d >> 3) & 3, e = d & 7;
                base[(((size_t)blk * 2 + half) * 64 + lkk * 16 + rr) * 8 + e] = v;
            } else {
                ushort* base = ws + VF_OFF + (size_t)fb * 262144;
                int kb64 = n >> 6, kc = n & 63;
                int hf = kc >> 5, lkv = (kc >> 3) & 3, ev = kc & 7;
                int dt = d >> 4, lav = d & 15;
                base[((((size_t)kb64 * 4 + dt) * 2 + hf) * 64 + lkv * 16 + lav) * 8 + ev] = v;
            }
        }
    }
}

// ---------------- kernel 2: masked attention, counted-vmcnt pipeline ----------------
// grid 2048: h = bid&7 (XCD-pinned), qb = (bid>>3)&63, ks = bid>>9 (0..3).
// 4 waves x 16 q-rows; 16 bodies of 64 keys.
// Per body (issue order pinned): [vmcnt(16); barrier] -> fmask from adjX ->
// STAGE(next K/V -> LDS, 4 ops) -> reissue adjX <- body+2 (16 ops) -> compute.
// FIFO at body top: [adjX16, stage4, adjY16] = 36 -> vmcnt(16) drains exactly
// adjX+stage, keeps adjY in flight ACROSS the barrier (T3/T4). adj cover = 2 bodies.

#define STAGE(BUF, KB)                                                                     \
    {                                                                                      \
        const ushort* sbase_ = (wave < 2) ? Kh : Vh;                                       \
        ushort(*dbuf_)[512] = (wave < 2) ? kbuf[BUF] : vbuf[BUF];                          \
        int t0_ = (wave & 1) * 4;                                                          \
        _Pragma("unroll")                                                                  \
        for (int t_ = 0; t_ < 4; ++t_) {                                                   \
            int tile_ = t0_ + t_;                                                          \
            const ushort* src_ = sbase_ +                                                  \
                (((size_t)(KB) * 4 + (tile_ >> 1)) * 2 + (tile_ & 1)) * 512 + lane * 8;    \
            __builtin_amdgcn_global_load_lds(                                              \
                (const __attribute__((address_space(1))) unsigned int*)src_,               \
                (__attribute__((address_space(3))) unsigned int*)&dbuf_[tile_][0],         \
                16, 0, 0);                                                                 \
        }                                                                                  \
    }

// ADJ: register mask buffer consumed this body. KB: body index.
// DOSTAGE/DOADJ: literal 0/1. SKB: body staged (=KB+1). AKB: adj reissue body (=KB+2).
// VM: literal vmcnt immediate for the top wait.
#define BODY(ADJ, KB, DOSTAGE, SKB, DOADJ, AKB, VM)                                        \
    {                                                                                      \
        asm volatile("s_waitcnt vmcnt(" #VM ")" ::: "memory");                             \
        __builtin_amdgcn_s_barrier();                                                      \
        const int cur_ = (KB) & 1;                                                         \
        float fmask[16];                                                                   \
        _Pragma("unroll")                                                                  \
        for (int j = 0; j < 16; ++j) fmask[j] = ADJ[j] ? 0.f : -1e30f;                     \
        __builtin_amdgcn_sched_barrier(0);                                                 \
        if (DOSTAGE) STAGE(((KB) + 1) & 1, SKB)                                            \
        __builtin_amdgcn_sched_barrier(0);                                                 \
        if (DOADJ) {                                                                       \
            _Pragma("unroll")                                                              \
            for (int kt = 0; kt < 4; ++kt)                                                 \
                _Pragma("unroll")                                                          \
                for (int r = 0; r < 4; ++r)                                                \
                    ADJ[kt * 4 + r] = __builtin_nontemporal_load(                          \
                        adjw + (size_t)(lk * 4 + r) * 4096 + (size_t)(AKB) * 64 + kt * 16 + la); \
        }                                                                                  \
        __builtin_amdgcn_sched_barrier(0);                                                 \
        f32x4 s[4];                                                                        \
        _Pragma("unroll")                                                                  \
        for (int kt = 0; kt < 4; ++kt) {                                                   \
            bf16x8 kf0 = *reinterpret_cast<const bf16x8*>(&kbuf[cur_][kt * 2 + 0][lane * 8]); \
            bf16x8 kf1 = *reinterpret_cast<const bf16x8*>(&kbuf[cur_][kt * 2 + 1][lane * 8]); \
            s[kt] = __builtin_amdgcn_mfma_f32_16x16x32_bf16(qa0, kf0, zero, 0, 0, 0);      \
            s[kt] = __builtin_amdgcn_mfma_f32_16x16x32_bf16(qa1, kf1, s[kt], 0, 0, 0);     \
        }                                                                                  \
        _Pragma("unroll")                                                                  \
        for (int kt = 0; kt < 4; ++kt)                                                     \
            _Pragma("unroll")                                                              \
            for (int r = 0; r < 4; ++r) {                                                  \
                float e = __expf(s[kt][r] + fmask[kt * 4 + r]);                            \
                den[r] += e;                                                               \
                P[wave][lk * 4 + r][kt * 16 + la] = f2bf(e);                               \
            }                                                                              \
        bf16x8 pa0 = *reinterpret_cast<const bf16x8*>(&P[wave][la][lk * 8]);               \
        bf16x8 pa1 = *reinterpret_cast<const bf16x8*>(&P[wave][la][32 + lk * 8]);          \
        _Pragma("unroll")                                                                  \
        for (int dt = 0; dt < 4; ++dt) {                                                   \
            bf16x8 vb0 = *reinterpret_cast<const bf16x8*>(&vbuf[cur_][dt * 2 + 0][lane * 8]); \
            bf16x8 vb1 = *reinterpret_cast<const bf16x8*>(&vbuf[cur_][dt * 2 + 1][lane * 8]); \
            acc[dt] = __builtin_amdgcn_mfma_f32_16x16x32_bf16(pa0, vb0, acc[dt], 0, 0, 0); \
            acc[dt] = __builtin_amdgcn_mfma_f32_16x16x32_bf16(pa1, vb1, acc[dt], 0, 0, 0); \
        }                                                                                  \
    }

__global__ __launch_bounds__(256, 3) void attn_kernel(const int* __restrict__ adj,
                                                      const ushort* __restrict__ ws,
                                                      ushort* __restrict__ pacc,
                                                      float* __restrict__ pden) {
    __shared__ ushort kbuf[2][8][512];   // 16KB
    __shared__ ushort vbuf[2][8][512];   // 16KB
    __shared__ ushort P[4][16][72];      // 9.2KB per-wave P staging

    int bid = blockIdx.x;
    int h = bid & 7, qb = (bid >> 3) & 63, ks = bid >> 9;
    int wave = threadIdx.x >> 6, lane = threadIdx.x & 63;
    int la = lane & 15, lk = lane >> 4;
    int q0w = qb * 64 + wave * 16;

    const ushort* Qh = ws + QF_OFF + (size_t)h * 262144;
    const ushort* Kh = ws + KF_OFF + (size_t)h * 262144;
    const ushort* Vh = ws + VF_OFF + (size_t)h * 262144;
    const int* adjw = adj + (size_t)h * 16777216 + (size_t)q0w * 4096;

    bf16x8 qa0 = *reinterpret_cast<const bf16x8*>(Qh + ((((size_t)(q0w >> 4)) * 2 + 0) * 64 + lane) * 8);
    bf16x8 qa1 = *reinterpret_cast<const bf16x8*>(Qh + ((((size_t)(q0w >> 4)) * 2 + 1) * 64 + lane) * 8);

    f32x4 acc[4];
    float den[4];
#pragma unroll
    for (int r = 0; r < 4; ++r) {
        acc[r] = (f32x4){0.f, 0.f, 0.f, 0.f};
        den[r] = 0.f;
    }

    const f32x4 zero = {0.f, 0.f, 0.f, 0.f};
    int kbase = ks * 16;   // bodies kbase .. kbase+15 (64 keys each)

    // prologue — FIFO order must be [adjA16, stage4, adjB16]:
    int adjA[16], adjB[16];
#pragma unroll
    for (int kt = 0; kt < 4; ++kt)
#pragma unroll
        for (int r = 0; r < 4; ++r)
            adjA[kt * 4 + r] = __builtin_nontemporal_load(
                adjw + (size_t)(lk * 4 + r) * 4096 + (size_t)kbase * 64 + kt * 16 + la);
    __builtin_amdgcn_sched_barrier(0);
    STAGE(0, kbase)
    __builtin_amdgcn_sched_barrier(0);
#pragma unroll
    for (int kt = 0; kt < 4; ++kt)
#pragma unroll
        for (int r = 0; r < 4; ++r)
            adjB[kt * 4 + r] = __builtin_nontemporal_load(
                adjw + (size_t)(lk * 4 + r) * 4096 + (size_t)(kbase + 1) * 64 + kt * 16 + la);
    __builtin_amdgcn_sched_barrier(0);

    // main loop: bodies 0..13 (steady state), bodies 14/15 peeled with exact counts
    for (int it = 0; it < 14; it += 2) {
        int kbA = kbase + it;
        BODY(adjA, kbA,     1, kbA + 1, 1, kbA + 2, 16)
        BODY(adjB, kbA + 1, 1, kbA + 2, 1, kbA + 3, 16)
    }
    BODY(adjA, kbase + 14, 1, kbase + 15, 0, 0, 16)
    BODY(adjB, kbase + 15, 0, 0,          0, 0, 0)

    // reduce den over the 16-lane key dimension
#pragma unroll
    for (int r = 0; r < 4; ++r)
#pragma unroll
        for (int mm = 1; mm < 16; mm <<= 1)
            den[r] += __shfl_xor(den[r], mm, 64);

    // store bf16 partial acc + f32 partial den
    ushort* pa_out = pacc + ((size_t)ks * 8 + h) * 4096 * 64;
#pragma unroll
    for (int dt = 0; dt < 4; ++dt)
#pragma unroll
        for (int r = 0; r < 4; ++r) {
            int q = q0w + lk * 4 + r;
            __builtin_nontemporal_store(f2bf(acc[dt][r]), pa_out + (size_t)q * 64 + dt * 16 + la);
        }
    if (la == 0) {
        float* pd = pden + ((size_t)ks * 8 + h) * 4096;
#pragma unroll
        for (int r = 0; r < 4; ++r)
            pd[q0w + lk * 4 + r] = den[r];
    }
}

// ---------------- kernel 3: combine bf16 partials + epilogue ----------------
__global__ __launch_bounds__(256) void combine_kernel(const float* __restrict__ x,
                                                      const ushort* __restrict__ pacc,
                                                      const float* __restrict__ pden,
                                                      float* __restrict__ out) {
    int idx = blockIdx.x * 256 + threadIdx.x;   // 524288 total
    int n = idx >> 7, fq = idx & 127;
    int h = fq >> 4;
    int d4 = (fq & 15) * 4;

    float4 o = make_float4(0.f, 0.f, 0.f, 0.f);
    float den = 0.f;
#pragma unroll
    for (int ksp = 0; ksp < 4; ++ksp) {
        const ushort* pa = pacc + (((size_t)ksp * 8 + h) * 4096 + n) * 64 + d4;
        ushort4 p = *reinterpret_cast<const ushort4*>(pa);
        o.x += bf2f(p.x); o.y += bf2f(p.y); o.z += bf2f(p.z); o.w += bf2f(p.w);
        den += pden[((size_t)ksp * 8 + h) * 4096 + n];
    }
    float4 xv = *reinterpret_cast<const float4*>(x + (size_t)n * 512 + fq * 4);
    float inv = 1.f / den;
    float4 r;
    r.x = o.x * inv + xv.x;
    r.y = o.y * inv + xv.y;
    r.z = o.z * inv + xv.z;
    r.w = o.w * inv + xv.w;
    r.x = (r.x > 0.f) ? r.x : (__expf(r.x) - 1.f);
    r.y = (r.y > 0.f) ? r.y : (__expf(r.y) - 1.f);
    r.z = (r.z > 0.f) ? r.z : (__expf(r.z) - 1.f);
    r.w = (r.w > 0.f) ? r.w : (__expf(r.w) - 1.f);
    *reinterpret_cast<float4*>(out + (size_t)n * 512 + fq * 4) = r;
}

extern "C" void kernel_launch(void* const* d_in, const int* in_sizes, int n_in,
                              void* d_out, int out_size, void* d_ws, size_t ws_size,
                              hipStream_t stream) {
    const float* x  = (const float*)d_in[0];
    const float* wq = (const float*)d_in[1];
    const float* wk = (const float*)d_in[2];
    const float* wv = (const float*)d_in[3];
    const int*   adj = (const int*)d_in[4];
    float* out = (float*)d_out;
    ushort* ws = (ushort*)d_ws;
    ushort* pacc = ws + PACC_OFF;
    float* pden = (float*)(ws + PDEN_USHORT_OFF);

    cvt_kernel<<<2816, 256, 0, stream>>>(x, wq, wk, wv, ws);
    qkv_kernel<<<dim3(24, 64), 256, 0, stream>>>(ws);
    attn_kernel<<<2048, 256, 0, stream>>>(adj, ws, pacc, pden);
    combine_kernel<<<2048, 256, 0, stream>>>(x, pacc, pden, out);
}